// Round 4
// baseline (632.816 us; speedup 1.0000x reference)
//
#include <hip/hip_runtime.h>

#define B 16384
#define ENC_LEN 48
#define ENC_HID 128
#define T_DEC 12

__device__ __forceinline__ float fast_rcp(float x) { return __builtin_amdgcn_rcpf(x); }
__device__ __forceinline__ float fast_exp(float x) { return __expf(x); }
__device__ __forceinline__ float sigmoidf_(float x) { return fast_rcp(1.f + fast_exp(-x)); }
__device__ __forceinline__ float tanhf_(float x) {
    // 1 - 2/(e^{2x}+1); correct saturation for |x| large
    return 1.f - 2.f * fast_rcp(1.f + fast_exp(2.f * x));
}
__device__ __forceinline__ float nan_to_num_(float v) { return (v != v) ? 0.f : v; }
__device__ __forceinline__ float dot4(float4 a, float4 b) {
    return a.x * b.x + a.y * b.y + a.z * b.z + a.w * b.w;
}

// ---------------- precompute P (unchanged — HBM-bound at ~70 us, floor 64) ----------------
// P[e*B + b] = float4( enc_row(e,b) . comb_W[i, 0:128] ), i = 0..3
__global__ __launch_bounds__(256) void precompute_P_kernel(
    const float* __restrict__ enc,    // (48, B, 128) f32
    const float* __restrict__ cW,     // (4, 132) f32
    float4* __restrict__ P)
{
    const int l = threadIdx.x & 7;
    const int rowLocal = threadIdx.x >> 3;

    float w[4][4][4];
    #pragma unroll
    for (int i = 0; i < 4; ++i)
        #pragma unroll
        for (int k = 0; k < 4; ++k) {
            float4 t = *(const float4*)(cW + i * 132 + k * 32 + l * 4);
            w[i][k][0] = t.x; w[i][k][1] = t.y; w[i][k][2] = t.z; w[i][k][3] = t.w;
        }

    const int totalRows = ENC_LEN * B;
    const int stride = gridDim.x * 32;
    for (int row = blockIdx.x * 32 + rowLocal; row < totalRows; row += stride) {
        const float* r = enc + (size_t)row * ENC_HID;
        float4 e[4];
        #pragma unroll
        for (int k = 0; k < 4; ++k)
            e[k] = *(const float4*)(r + k * 32 + l * 4);

        float a[4];
        #pragma unroll
        for (int i = 0; i < 4; ++i) {
            float s0 = e[0].x * w[i][0][0] + e[0].y * w[i][0][1] + e[0].z * w[i][0][2] + e[0].w * w[i][0][3];
            float s1 = e[1].x * w[i][1][0] + e[1].y * w[i][1][1] + e[1].z * w[i][1][2] + e[1].w * w[i][1][3];
            float s2 = e[2].x * w[i][2][0] + e[2].y * w[i][2][1] + e[2].z * w[i][2][2] + e[2].w * w[i][2][3];
            float s3 = e[3].x * w[i][3][0] + e[3].y * w[i][3][1] + e[3].z * w[i][3][2] + e[3].w * w[i][3][3];
            a[i] = (s0 + s1) + (s2 + s3);
        }
        #pragma unroll
        for (int m = 1; m < 8; m <<= 1) {
            #pragma unroll
            for (int i = 0; i < 4; ++i)
                a[i] += __shfl_xor(a[i], m, 8);
        }
        if (l == 0) P[row] = make_float4(a[0], a[1], a[2], a[3]);
    }
}

// ---------------- barrier-free decode, G=2 (two batch elements per lane) ----------------
// 16 lanes per group, each group serves b0 = 32*blk + 2*gi and b1 = b0+1.
// Lane q owns attention rows 3q..3q+2 and GRU units {q, q+16} for BOTH b's.
// Rationale (round-3 counters): decode was LDS-throughput-bound — 72 weight
// quads re-read per lane per step served ONE b. Now each quad feeds two dot
// products -> LDS traffic per b ~halved. Small t-invariant weights (wih, aW
// x-part) are deliberately preloaded into registers. The asm launder on qv
// stays: without it LICM hoists the big weight arrays into 288+ registers and
// spills (round-2: 1.1 GB scratch traffic).
// Grid 512 blocks x 256 thr = 2 blocks/CU, 8 waves/CU; VGPR cap 256 at (256,2).
__global__ __launch_bounds__(256, 2) void decode_kernel(
    const float* __restrict__ y,        // (B,13,4)
    const float* __restrict__ hidden,   // (B,32)
    const float4* __restrict__ P,       // (48,B) f32x4
    const float* __restrict__ aW,       // (48,36)
    const float* __restrict__ ab,       // (48)
    const float* __restrict__ cW,       // (4,132)
    const float* __restrict__ cb,       // (4)
    const float* __restrict__ wih,      // (96,4)
    const float* __restrict__ whh,      // (96,32)
    const float* __restrict__ bih,      // (96)
    const float* __restrict__ bhh,      // (96)
    const float* __restrict__ fW,       // (32)
    const float* __restrict__ fb,       // (1)
    float* __restrict__ out)            // (12,B)
{
    __shared__ __align__(16) float aW_l[48 * 36];      // row e: [0:4] unused here, [4:36]=h-w
    __shared__ __align__(16) float whh_l[96 * 36];     // row r: [0:32] used, pad 4
    __shared__ __align__(16) float hbuf[4][4][2][36];  // [wave][grp][b-sel][unit 0:32]

    const int tid = threadIdx.x;

    // ---- one-time weight staging (only sync in the kernel) ----
    for (int i = tid; i < 48 * 36; i += 256) aW_l[i] = aW[i];
    for (int i = tid; i < 96 * 32; i += 256) whh_l[(i >> 5) * 36 + (i & 31)] = whh[i];

    const int lane = tid & 63;
    const int q    = lane & 15;          // role within 16-lane group
    const int w    = tid >> 6;           // wave id within block
    const int grp  = lane >> 4;          // group within wave
    const int gi   = tid >> 4;           // group within block (0..15)
    const int b0   = blockIdx.x * 32 + 2 * gi;
    const int b1   = b0 + 1;

    // ---- t-invariant per-lane data deliberately held in registers ----
    const float4 pb0a = P[(size_t)(3 * q + 0) * B + b0];
    const float4 pb1a = P[(size_t)(3 * q + 1) * B + b0];
    const float4 pb2a = P[(size_t)(3 * q + 2) * B + b0];
    const float4 pb0b = P[(size_t)(3 * q + 0) * B + b1];
    const float4 pb1b = P[(size_t)(3 * q + 1) * B + b1];
    const float4 pb2b = P[(size_t)(3 * q + 2) * B + b1];

    float h0a = hidden[(size_t)b0 * 32 + q];
    float h1a = hidden[(size_t)b0 * 32 + q + 16];
    float h0b = hidden[(size_t)b1 * 32 + q];
    float h1b = hidden[(size_t)b1 * 32 + q + 16];

    float xa0 = nan_to_num_(y[(size_t)b0 * 52 + 0]);
    float xa1 = nan_to_num_(y[(size_t)b0 * 52 + 1]);
    float xa2 = nan_to_num_(y[(size_t)b0 * 52 + 2]);
    float xa3 = nan_to_num_(y[(size_t)b0 * 52 + 3]);
    float xb0 = nan_to_num_(y[(size_t)b1 * 52 + 0]);
    float xb1 = nan_to_num_(y[(size_t)b1 * 52 + 1]);
    float xb2 = nan_to_num_(y[(size_t)b1 * 52 + 2]);
    float xb3 = nan_to_num_(y[(size_t)b1 * 52 + 3]);

    // attention x-part weight quads (aW rows 3q..3q+2, cols 0:4) -> registers
    const float4 ax0 = *(const float4*)(aW + (3 * q + 0) * 36);
    const float4 ax1 = *(const float4*)(aW + (3 * q + 1) * 36);
    const float4 ax2 = *(const float4*)(aW + (3 * q + 2) * 36);

    // GRU input weights (wih rows for units q, q+16, all 3 gates) -> registers
    const float4 wiR0 = *(const float4*)(wih + (size_t)(q +  0) * 4);
    const float4 wiZ0 = *(const float4*)(wih + (size_t)(q + 32) * 4);
    const float4 wiN0 = *(const float4*)(wih + (size_t)(q + 64) * 4);
    const float4 wiR1 = *(const float4*)(wih + (size_t)(q + 16) * 4);
    const float4 wiZ1 = *(const float4*)(wih + (size_t)(q + 48) * 4);
    const float4 wiN1 = *(const float4*)(wih + (size_t)(q + 80) * 4);

    const float ab0 = ab[3 * q + 0], ab1 = ab[3 * q + 1], ab2 = ab[3 * q + 2];
    const float bi_r0 = bih[q],      bi_z0 = bih[q + 32], bi_n0 = bih[q + 64];
    const float bi_r1 = bih[q + 16], bi_z1 = bih[q + 48], bi_n1 = bih[q + 80];
    const float bh_r0 = bhh[q],      bh_z0 = bhh[q + 32], bh_n0 = bhh[q + 64];
    const float bh_r1 = bhh[q + 16], bh_z1 = bhh[q + 48], bh_n1 = bhh[q + 80];
    const float fw0 = fW[q], fw1 = fW[q + 16];
    const float fb0 = fb[0];
    float cWt[16], cbv[4];
    #pragma unroll
    for (int i = 0; i < 4; ++i) {
        cbv[i] = cb[i];
        #pragma unroll
        for (int k = 0; k < 4; ++k) cWt[i * 4 + k] = cW[i * 132 + 128 + k];
    }

    __syncthreads();

    float* hra = &hbuf[w][grp][0][0];
    float* hrb = &hbuf[w][grp][1][0];

    int qv = q;   // opaque role index: re-laundered every iteration

    #pragma unroll 1
    for (int t = 0; t < T_DEC; ++t) {
        // launder qv so the big weight addresses below are NOT loop-invariant
        asm volatile("" : "+v"(qv));

        const float4* pa0  = (const float4*)(aW_l + (3 * qv + 0) * 36 + 4);
        const float4* pa1  = (const float4*)(aW_l + (3 * qv + 1) * 36 + 4);
        const float4* pa2  = (const float4*)(aW_l + (3 * qv + 2) * 36 + 4);
        const float4* pw0r = (const float4*)(whh_l + (size_t)(qv +  0) * 36);
        const float4* pw0z = (const float4*)(whh_l + (size_t)(qv + 32) * 36);
        const float4* pw0n = (const float4*)(whh_l + (size_t)(qv + 64) * 36);
        const float4* pw1r = (const float4*)(whh_l + (size_t)(qv + 16) * 36);
        const float4* pw1z = (const float4*)(whh_l + (size_t)(qv + 48) * 36);
        const float4* pw1n = (const float4*)(whh_l + (size_t)(qv + 80) * 36);

        // prefetch next y rows early (hide HBM/L2 latency under this step)
        float4 yva = make_float4(0.f, 0.f, 0.f, 0.f);
        float4 yvb = make_float4(0.f, 0.f, 0.f, 0.f);
        if (t < T_DEC - 1) {
            yva = *(const float4*)(y + (size_t)b0 * 52 + (t + 1) * 4);
            yvb = *(const float4*)(y + (size_t)b1 * 52 + (t + 1) * 4);
        }

        // publish h (wave-synchronous, no barrier; 2-way bank alias = free)
        hra[q] = h0a; hra[q + 16] = h1a;
        hrb[q] = h0b; hrb[q + 16] = h1b;

        // ---- fused c-loop: each weight quad feeds TWO dot products ----
        float s0a = 0.f, s1a = 0.f, s2a = 0.f;
        float s0b = 0.f, s1b = 0.f, s2b = 0.f;
        float gr0a = bh_r0, gz0a = bh_z0, gn0a = bh_n0;
        float gr1a = bh_r1, gz1a = bh_z1, gn1a = bh_n1;
        float gr0b = bh_r0, gz0b = bh_z0, gn0b = bh_n0;
        float gr1b = bh_r1, gz1b = bh_z1, gn1b = bh_n1;
        #pragma unroll
        for (int c = 0; c < 8; ++c) {
            const float4 hvA = *(const float4*)(hra + 4 * c);
            const float4 hvB = *(const float4*)(hrb + 4 * c);
            float4 wv;
            wv = pa0[c];  s0a  += dot4(wv, hvA); s0b  += dot4(wv, hvB);
            wv = pa1[c];  s1a  += dot4(wv, hvA); s1b  += dot4(wv, hvB);
            wv = pa2[c];  s2a  += dot4(wv, hvA); s2b  += dot4(wv, hvB);
            wv = pw0r[c]; gr0a += dot4(wv, hvA); gr0b += dot4(wv, hvB);
            wv = pw0z[c]; gz0a += dot4(wv, hvA); gz0b += dot4(wv, hvB);
            wv = pw0n[c]; gn0a += dot4(wv, hvA); gn0b += dot4(wv, hvB);
            wv = pw1r[c]; gr1a += dot4(wv, hvA); gr1b += dot4(wv, hvB);
            wv = pw1z[c]; gz1a += dot4(wv, hvA); gz1b += dot4(wv, hvB);
            wv = pw1n[c]; gn1a += dot4(wv, hvA); gn1b += dot4(wv, hvB);
        }

        // ---- attention finish: x-part (register quads) + bias, exp ----
        const float g0a = fast_exp(s0a + ab0 + ax0.x * xa0 + ax0.y * xa1 + ax0.z * xa2 + ax0.w * xa3);
        const float g1a = fast_exp(s1a + ab1 + ax1.x * xa0 + ax1.y * xa1 + ax1.z * xa2 + ax1.w * xa3);
        const float g2a = fast_exp(s2a + ab2 + ax2.x * xa0 + ax2.y * xa1 + ax2.z * xa2 + ax2.w * xa3);
        const float g0b = fast_exp(s0b + ab0 + ax0.x * xb0 + ax0.y * xb1 + ax0.z * xb2 + ax0.w * xb3);
        const float g1b = fast_exp(s1b + ab1 + ax1.x * xb0 + ax1.y * xb1 + ax1.z * xb2 + ax1.w * xb3);
        const float g2b = fast_exp(s2b + ab2 + ax2.x * xb0 + ax2.y * xb1 + ax2.z * xb2 + ax2.w * xb3);

        float SpA = g0a + g1a + g2a;
        float c0A = g0a * pb0a.x + g1a * pb1a.x + g2a * pb2a.x;
        float c1A = g0a * pb0a.y + g1a * pb1a.y + g2a * pb2a.y;
        float c2A = g0a * pb0a.z + g1a * pb1a.z + g2a * pb2a.z;
        float c3A = g0a * pb0a.w + g1a * pb1a.w + g2a * pb2a.w;
        float SpB = g0b + g1b + g2b;
        float c0B = g0b * pb0b.x + g1b * pb1b.x + g2b * pb2b.x;
        float c1B = g0b * pb0b.y + g1b * pb1b.y + g2b * pb2b.y;
        float c2B = g0b * pb0b.z + g1b * pb1b.z + g2b * pb2b.z;
        float c3B = g0b * pb0b.w + g1b * pb1b.w + g2b * pb2b.w;

        // butterfly-reduce across the 16-lane group (masks <16 stay in-group)
        #pragma unroll
        for (int m = 1; m < 16; m <<= 1) {
            SpA += __shfl_xor(SpA, m); SpB += __shfl_xor(SpB, m);
            c0A += __shfl_xor(c0A, m); c0B += __shfl_xor(c0B, m);
            c1A += __shfl_xor(c1A, m); c1B += __shfl_xor(c1B, m);
            c2A += __shfl_xor(c2A, m); c2B += __shfl_xor(c2B, m);
            c3A += __shfl_xor(c3A, m); c3B += __shfl_xor(c3B, m);
        }
        const float rsA = fast_rcp(SpA);
        const float rsB = fast_rcp(SpB);

        const float x20a = c0A * rsA + cWt[ 0] * xa0 + cWt[ 1] * xa1 + cWt[ 2] * xa2 + cWt[ 3] * xa3 + cbv[0];
        const float x21a = c1A * rsA + cWt[ 4] * xa0 + cWt[ 5] * xa1 + cWt[ 6] * xa2 + cWt[ 7] * xa3 + cbv[1];
        const float x22a = c2A * rsA + cWt[ 8] * xa0 + cWt[ 9] * xa1 + cWt[10] * xa2 + cWt[11] * xa3 + cbv[2];
        const float x23a = c3A * rsA + cWt[12] * xa0 + cWt[13] * xa1 + cWt[14] * xa2 + cWt[15] * xa3 + cbv[3];
        const float x20b = c0B * rsB + cWt[ 0] * xb0 + cWt[ 1] * xb1 + cWt[ 2] * xb2 + cWt[ 3] * xb3 + cbv[0];
        const float x21b = c1B * rsB + cWt[ 4] * xb0 + cWt[ 5] * xb1 + cWt[ 6] * xb2 + cWt[ 7] * xb3 + cbv[1];
        const float x22b = c2B * rsB + cWt[ 8] * xb0 + cWt[ 9] * xb1 + cWt[10] * xb2 + cWt[11] * xb3 + cbv[2];
        const float x23b = c3B * rsB + cWt[12] * xb0 + cWt[13] * xb1 + cWt[14] * xb2 + cWt[15] * xb3 + cbv[3];

        // ---- GRU finish (wih in registers) ----
        const float ir0a = bi_r0 + wiR0.x * x20a + wiR0.y * x21a + wiR0.z * x22a + wiR0.w * x23a;
        const float iz0a = bi_z0 + wiZ0.x * x20a + wiZ0.y * x21a + wiZ0.z * x22a + wiZ0.w * x23a;
        const float in0a = bi_n0 + wiN0.x * x20a + wiN0.y * x21a + wiN0.z * x22a + wiN0.w * x23a;
        const float ir1a = bi_r1 + wiR1.x * x20a + wiR1.y * x21a + wiR1.z * x22a + wiR1.w * x23a;
        const float iz1a = bi_z1 + wiZ1.x * x20a + wiZ1.y * x21a + wiZ1.z * x22a + wiZ1.w * x23a;
        const float in1a = bi_n1 + wiN1.x * x20a + wiN1.y * x21a + wiN1.z * x22a + wiN1.w * x23a;
        const float ir0b = bi_r0 + wiR0.x * x20b + wiR0.y * x21b + wiR0.z * x22b + wiR0.w * x23b;
        const float iz0b = bi_z0 + wiZ0.x * x20b + wiZ0.y * x21b + wiZ0.z * x22b + wiZ0.w * x23b;
        const float in0b = bi_n0 + wiN0.x * x20b + wiN0.y * x21b + wiN0.z * x22b + wiN0.w * x23b;
        const float ir1b = bi_r1 + wiR1.x * x20b + wiR1.y * x21b + wiR1.z * x22b + wiR1.w * x23b;
        const float iz1b = bi_z1 + wiZ1.x * x20b + wiZ1.y * x21b + wiZ1.z * x22b + wiZ1.w * x23b;
        const float in1b = bi_n1 + wiN1.x * x20b + wiN1.y * x21b + wiN1.z * x22b + wiN1.w * x23b;

        const float r0a = sigmoidf_(ir0a + gr0a);
        const float z0a = sigmoidf_(iz0a + gz0a);
        const float n0a = tanhf_(in0a + r0a * gn0a);
        const float hn0a = (1.f - z0a) * n0a + z0a * h0a;
        const float r1a = sigmoidf_(ir1a + gr1a);
        const float z1a = sigmoidf_(iz1a + gz1a);
        const float n1a = tanhf_(in1a + r1a * gn1a);
        const float hn1a = (1.f - z1a) * n1a + z1a * h1a;

        const float r0b = sigmoidf_(ir0b + gr0b);
        const float z0b = sigmoidf_(iz0b + gz0b);
        const float n0b = tanhf_(in0b + r0b * gn0b);
        const float hn0b = (1.f - z0b) * n0b + z0b * h0b;
        const float r1b = sigmoidf_(ir1b + gr1b);
        const float z1b = sigmoidf_(iz1b + gz1b);
        const float n1b = tanhf_(in1b + r1b * gn1b);
        const float hn1b = (1.f - z1b) * n1b + z1b * h1b;

        // ---- fc output (butterfly; every lane gets both o's for feedback) ----
        float opA = fw0 * hn0a + fw1 * hn1a;
        float opB = fw0 * hn0b + fw1 * hn1b;
        #pragma unroll
        for (int m = 1; m < 16; m <<= 1) {
            opA += __shfl_xor(opA, m);
            opB += __shfl_xor(opB, m);
        }
        const float oA = opA + fb0;
        const float oB = opB + fb0;
        if (q == 0) out[(size_t)t * B + b0] = oA;
        if (q == 1) out[(size_t)t * B + b1] = oB;

        h0a = hn0a; h1a = hn1a; h0b = hn0b; h1b = hn1b;
        if (t < T_DEC - 1) {
            xa0 = yva.y; xa1 = yva.z; xa2 = yva.w; xa3 = oA;
            xb0 = yvb.y; xb1 = yvb.z; xb2 = yvb.w; xb3 = oB;
        }
    }
}

extern "C" void kernel_launch(void* const* d_in, const int* in_sizes, int n_in,
                              void* d_out, int out_size, void* d_ws, size_t ws_size,
                              hipStream_t stream)
{
    const float* y   = (const float*)d_in[0];
    const float* enc = (const float*)d_in[1];
    const float* hid = (const float*)d_in[2];
    // d_in[3] = batch_ids (int32, unused by reference)
    const float* aW  = (const float*)d_in[4];
    const float* ab  = (const float*)d_in[5];
    const float* cW  = (const float*)d_in[6];
    const float* cb  = (const float*)d_in[7];
    const float* wih = (const float*)d_in[8];
    const float* whh = (const float*)d_in[9];
    const float* bih = (const float*)d_in[10];
    const float* bhh = (const float*)d_in[11];
    const float* fW  = (const float*)d_in[12];
    const float* fb  = (const float*)d_in[13];
    float* out = (float*)d_out;

    float4* P = (float4*)d_ws;   // 48*B float4 = 12.58 MB (ws proved sufficient)

    precompute_P_kernel<<<4096, 256, 0, stream>>>(enc, cW, P);
    decode_kernel<<<B / 32, 256, 0, stream>>>(
        y, hid, P, aW, ab, cW, cb, wih, whh, bih, bhh, fW, fb, out);
}

// Round 5
// 622.284 us; speedup vs baseline: 1.0169x; 1.0169x over previous
//
#include <hip/hip_runtime.h>

#define B 16384
#define ENC_LEN 48
#define ENC_HID 128
#define T_DEC 12

__device__ __forceinline__ float fast_rcp(float x) { return __builtin_amdgcn_rcpf(x); }
__device__ __forceinline__ float fast_exp(float x) { return __expf(x); }
__device__ __forceinline__ float sigmoidf_(float x) { return fast_rcp(1.f + fast_exp(-x)); }
__device__ __forceinline__ float tanhf_(float x) {
    // 1 - 2/(e^{2x}+1); correct saturation for |x| large
    return 1.f - 2.f * fast_rcp(1.f + fast_exp(2.f * x));
}
__device__ __forceinline__ float nan_to_num_(float v) { return (v != v) ? 0.f : v; }

// ---------------- fused P-precompute + barrier-free decode ----------------
// R4 lesson: G=2 (8 waves/CU) regressed -> decode is latency-hiding-bound,
// keep R3's G=1 / 16 waves/CU loop. This round fuses the P precompute into
// the decode kernel: each block computes P for its own 16 b's (768 rows)
// from enc into LDS (phase 0, HBM-bound), then runs the R3 decode loop
// (VALU/LDS-bound). Staggered block progress overlaps the two regimes, and
// the 12.6 MB P round-trip through HBM disappears (d_ws now unused).
//
// Phase 0: 8 lanes per P row (cW slice held in 64 regs/lane), coalesced
// 512 B enc row reads, 8-lane shfl_xor reduce, lane 0 writes LDS.
// Decode: lane q owns attn rows 3q..3q+2 + GRU units {q,q+16}; h exchanged
// via per-wave LDS (wave-synchronous, zero barriers in the t-loop); the asm
// launder on qv stays (round-2: without it LICM hoists 288 regs of weights
// and spills 1.1 GB of scratch traffic).
__global__ __launch_bounds__(256, 4) void fused_kernel(
    const float* __restrict__ y,        // (B,13,4)
    const float* __restrict__ hidden,   // (B,32)
    const float* __restrict__ enc,      // (48,B,128)
    const float* __restrict__ aW,       // (48,36)
    const float* __restrict__ ab,       // (48)
    const float* __restrict__ cW,       // (4,132)
    const float* __restrict__ cb,       // (4)
    const float* __restrict__ wih,      // (96,4)
    const float* __restrict__ whh,      // (96,32)
    const float* __restrict__ bih,      // (96)
    const float* __restrict__ bhh,      // (96)
    const float* __restrict__ fW,       // (32)
    const float* __restrict__ fb,       // (1)
    float* __restrict__ out)            // (12,B)
{
    __shared__ __align__(16) float aW_l[48 * 36];    // row e: [0:4]=x-w, [4:36]=h-w
    __shared__ __align__(16) float whh_l[96 * 36];   // row r: [0:32] used, pad 4
    __shared__ __align__(16) float hbuf[4][144];     // [wave][grp*36 + unit]
    __shared__ __align__(16) float4 P_l[ENC_LEN * 16];  // [e*16 + bLocal]

    const int tid = threadIdx.x;

    // ---- stage decode weights (overlaps with phase 0 below) ----
    for (int i = tid; i < 48 * 36; i += 256) aW_l[i] = aW[i];
    for (int i = tid; i < 96 * 32; i += 256) whh_l[(i >> 5) * 36 + (i & 31)] = whh[i];

    // ---- phase 0: P rows for this block's 16 b's (768 rows, 24 passes) ----
    {
        const int l = tid & 7;          // lane within 8-lane row cluster
        const int rowLocal = tid >> 3;  // 0..31: rows per pass
        const int bBase = blockIdx.x * 16;

        float w[4][4][4];
        #pragma unroll
        for (int i = 0; i < 4; ++i)
            #pragma unroll
            for (int k = 0; k < 4; ++k) {
                float4 t = *(const float4*)(cW + i * 132 + k * 32 + l * 4);
                w[i][k][0] = t.x; w[i][k][1] = t.y; w[i][k][2] = t.z; w[i][k][3] = t.w;
            }

        #pragma unroll 2
        for (int p = 0; p < 24; ++p) {
            const int rho = p * 32 + rowLocal;      // 0..767
            const int e   = rho >> 4;
            const int bL  = rho & 15;
            const float* r = enc + ((size_t)e * B + bBase + bL) * ENC_HID;
            float4 e4[4];
            #pragma unroll
            for (int k = 0; k < 4; ++k)
                e4[k] = *(const float4*)(r + k * 32 + l * 4);

            float a[4];
            #pragma unroll
            for (int i = 0; i < 4; ++i) {
                float s0 = e4[0].x * w[i][0][0] + e4[0].y * w[i][0][1] + e4[0].z * w[i][0][2] + e4[0].w * w[i][0][3];
                float s1 = e4[1].x * w[i][1][0] + e4[1].y * w[i][1][1] + e4[1].z * w[i][1][2] + e4[1].w * w[i][1][3];
                float s2 = e4[2].x * w[i][2][0] + e4[2].y * w[i][2][1] + e4[2].z * w[i][2][2] + e4[2].w * w[i][2][3];
                float s3 = e4[3].x * w[i][3][0] + e4[3].y * w[i][3][1] + e4[3].z * w[i][3][2] + e4[3].w * w[i][3][3];
                a[i] = (s0 + s1) + (s2 + s3);
            }
            #pragma unroll
            for (int m = 1; m < 8; m <<= 1) {
                #pragma unroll
                for (int i = 0; i < 4; ++i)
                    a[i] += __shfl_xor(a[i], m, 8);
            }
            if (l == 0) P_l[rho] = make_float4(a[0], a[1], a[2], a[3]);
        }
    }

    const int lane = tid & 63;
    const int q    = lane & 15;          // role within 16-lane group
    const int w    = tid >> 6;           // wave id within block
    const int grp  = lane >> 4;          // group (batch element) within wave
    const int gi   = tid >> 4;           // group within block (0..15)
    const int b    = blockIdx.x * 16 + gi;

    // ---- t-invariant per-lane data deliberately held in registers ----
    float h0 = hidden[(size_t)b * 32 + q];
    float h1 = hidden[(size_t)b * 32 + q + 16];

    float xA0 = nan_to_num_(y[(size_t)b * 52 + 0]);
    float xA1 = nan_to_num_(y[(size_t)b * 52 + 1]);
    float xA2 = nan_to_num_(y[(size_t)b * 52 + 2]);
    float xA3 = nan_to_num_(y[(size_t)b * 52 + 3]);

    // attention x-part weight quads -> registers (global, L2-hit)
    const float4 ax0 = *(const float4*)(aW + (3 * q + 0) * 36);
    const float4 ax1 = *(const float4*)(aW + (3 * q + 1) * 36);
    const float4 ax2 = *(const float4*)(aW + (3 * q + 2) * 36);

    // GRU input weights -> registers
    const float4 wiR0 = *(const float4*)(wih + (size_t)(q +  0) * 4);
    const float4 wiZ0 = *(const float4*)(wih + (size_t)(q + 32) * 4);
    const float4 wiN0 = *(const float4*)(wih + (size_t)(q + 64) * 4);
    const float4 wiR1 = *(const float4*)(wih + (size_t)(q + 16) * 4);
    const float4 wiZ1 = *(const float4*)(wih + (size_t)(q + 48) * 4);
    const float4 wiN1 = *(const float4*)(wih + (size_t)(q + 80) * 4);

    const float ab0 = ab[3 * q + 0], ab1 = ab[3 * q + 1], ab2 = ab[3 * q + 2];
    const float bi_r0 = bih[q],      bi_z0 = bih[q + 32], bi_n0 = bih[q + 64];
    const float bi_r1 = bih[q + 16], bi_z1 = bih[q + 48], bi_n1 = bih[q + 80];
    const float bh_r0 = bhh[q],      bh_z0 = bhh[q + 32], bh_n0 = bhh[q + 64];
    const float bh_r1 = bhh[q + 16], bh_z1 = bhh[q + 48], bh_n1 = bhh[q + 80];
    const float fw0 = fW[q], fw1 = fW[q + 16];
    const float fb0 = fb[0];
    float cWt[16], cbv[4];
    #pragma unroll
    for (int i = 0; i < 4; ++i) {
        cbv[i] = cb[i];
        #pragma unroll
        for (int k = 0; k < 4; ++k) cWt[i * 4 + k] = cW[i * 132 + 128 + k];
    }

    __syncthreads();   // P_l + aW_l/whh_l complete

    // P fragments for this lane's 3 attention rows, from LDS -> registers
    const float4 pb0 = P_l[(3 * q + 0) * 16 + gi];
    const float4 pb1 = P_l[(3 * q + 1) * 16 + gi];
    const float4 pb2 = P_l[(3 * q + 2) * 16 + gi];

    float* hrow = &hbuf[w][grp * 36];

    int qv = q;   // opaque role index: re-laundered every iteration

    #pragma unroll 1
    for (int t = 0; t < T_DEC; ++t) {
        // launder qv so the big weight addresses below are NOT loop-invariant
        asm volatile("" : "+v"(qv));

        const float4* pa0  = (const float4*)(aW_l + (3 * qv + 0) * 36 + 4);
        const float4* pa1  = (const float4*)(aW_l + (3 * qv + 1) * 36 + 4);
        const float4* pa2  = (const float4*)(aW_l + (3 * qv + 2) * 36 + 4);
        const float4* pw0r = (const float4*)(whh_l + (size_t)(qv +  0) * 36);
        const float4* pw0z = (const float4*)(whh_l + (size_t)(qv + 32) * 36);
        const float4* pw0n = (const float4*)(whh_l + (size_t)(qv + 64) * 36);
        const float4* pw1r = (const float4*)(whh_l + (size_t)(qv + 16) * 36);
        const float4* pw1z = (const float4*)(whh_l + (size_t)(qv + 48) * 36);
        const float4* pw1n = (const float4*)(whh_l + (size_t)(qv + 80) * 36);

        // prefetch next y row early (hides HBM/L2 latency under this step)
        float4 yv = make_float4(0.f, 0.f, 0.f, 0.f);
        if (t < T_DEC - 1) yv = *(const float4*)(y + (size_t)b * 52 + (t + 1) * 4);

        // publish h to the wave's group buffer (wave-synchronous, no barrier)
        hrow[q]      = h0;
        hrow[q + 16] = h1;

        // ---- fused c-loop: h float4 -> 9 accumulators, then dies ----
        float s0 = 0.f, s1 = 0.f, s2 = 0.f;
        float gr0 = bh_r0, gz0 = bh_z0, gn0 = bh_n0;
        float gr1 = bh_r1, gz1 = bh_z1, gn1 = bh_n1;
        #pragma unroll
        for (int c = 0; c < 8; ++c) {
            const float4 hv = *(const float4*)(hrow + 4 * c);
            float4 wv;
            wv = pa0[c];  s0  += wv.x * hv.x + wv.y * hv.y + wv.z * hv.z + wv.w * hv.w;
            wv = pa1[c];  s1  += wv.x * hv.x + wv.y * hv.y + wv.z * hv.z + wv.w * hv.w;
            wv = pa2[c];  s2  += wv.x * hv.x + wv.y * hv.y + wv.z * hv.z + wv.w * hv.w;
            wv = pw0r[c]; gr0 += wv.x * hv.x + wv.y * hv.y + wv.z * hv.z + wv.w * hv.w;
            wv = pw0z[c]; gz0 += wv.x * hv.x + wv.y * hv.y + wv.z * hv.z + wv.w * hv.w;
            wv = pw0n[c]; gn0 += wv.x * hv.x + wv.y * hv.y + wv.z * hv.z + wv.w * hv.w;
            wv = pw1r[c]; gr1 += wv.x * hv.x + wv.y * hv.y + wv.z * hv.z + wv.w * hv.w;
            wv = pw1z[c]; gz1 += wv.x * hv.x + wv.y * hv.y + wv.z * hv.z + wv.w * hv.w;
            wv = pw1n[c]; gn1 += wv.x * hv.x + wv.y * hv.y + wv.z * hv.z + wv.w * hv.w;
        }

        // ---- attention finish: x-part (register quads) + bias, exp ----
        const float g0 = fast_exp(s0 + ab0 + ax0.x * xA0 + ax0.y * xA1 + ax0.z * xA2 + ax0.w * xA3);
        const float g1 = fast_exp(s1 + ab1 + ax1.x * xA0 + ax1.y * xA1 + ax1.z * xA2 + ax1.w * xA3);
        const float g2 = fast_exp(s2 + ab2 + ax2.x * xA0 + ax2.y * xA1 + ax2.z * xA2 + ax2.w * xA3);

        float Sp = g0 + g1 + g2;
        float c0 = g0 * pb0.x + g1 * pb1.x + g2 * pb2.x;
        float c1 = g0 * pb0.y + g1 * pb1.y + g2 * pb2.y;
        float c2 = g0 * pb0.z + g1 * pb1.z + g2 * pb2.z;
        float c3 = g0 * pb0.w + g1 * pb1.w + g2 * pb2.w;

        // butterfly-reduce across the 16-lane group (all lanes get the sums)
        #pragma unroll
        for (int m = 1; m < 16; m <<= 1) {
            Sp += __shfl_xor(Sp, m);
            c0 += __shfl_xor(c0, m);
            c1 += __shfl_xor(c1, m);
            c2 += __shfl_xor(c2, m);
            c3 += __shfl_xor(c3, m);
        }
        const float rs = fast_rcp(Sp);

        const float x20 = c0 * rs + cWt[ 0] * xA0 + cWt[ 1] * xA1 + cWt[ 2] * xA2 + cWt[ 3] * xA3 + cbv[0];
        const float x21 = c1 * rs + cWt[ 4] * xA0 + cWt[ 5] * xA1 + cWt[ 6] * xA2 + cWt[ 7] * xA3 + cbv[1];
        const float x22 = c2 * rs + cWt[ 8] * xA0 + cWt[ 9] * xA1 + cWt[10] * xA2 + cWt[11] * xA3 + cbv[2];
        const float x23 = c3 * rs + cWt[12] * xA0 + cWt[13] * xA1 + cWt[14] * xA2 + cWt[15] * xA3 + cbv[3];

        // ---- GRU finish (wih in registers) ----
        const float ir0 = bi_r0 + wiR0.x * x20 + wiR0.y * x21 + wiR0.z * x22 + wiR0.w * x23;
        const float iz0 = bi_z0 + wiZ0.x * x20 + wiZ0.y * x21 + wiZ0.z * x22 + wiZ0.w * x23;
        const float in0 = bi_n0 + wiN0.x * x20 + wiN0.y * x21 + wiN0.z * x22 + wiN0.w * x23;
        const float ir1 = bi_r1 + wiR1.x * x20 + wiR1.y * x21 + wiR1.z * x22 + wiR1.w * x23;
        const float iz1 = bi_z1 + wiZ1.x * x20 + wiZ1.y * x21 + wiZ1.z * x22 + wiZ1.w * x23;
        const float in1 = bi_n1 + wiN1.x * x20 + wiN1.y * x21 + wiN1.z * x22 + wiN1.w * x23;

        const float r0 = sigmoidf_(ir0 + gr0);
        const float z0 = sigmoidf_(iz0 + gz0);
        const float n0 = tanhf_(in0 + r0 * gn0);
        const float hn0 = (1.f - z0) * n0 + z0 * h0;

        const float r1 = sigmoidf_(ir1 + gr1);
        const float z1 = sigmoidf_(iz1 + gz1);
        const float n1 = tanhf_(in1 + r1 * gn1);
        const float hn1 = (1.f - z1) * n1 + z1 * h1;

        // ---- fc output (butterfly; every lane gets o for the x feedback) ----
        float op = fw0 * hn0 + fw1 * hn1;
        #pragma unroll
        for (int m = 1; m < 16; m <<= 1) op += __shfl_xor(op, m);
        const float o = op + fb0;
        if (q == 0) out[(size_t)t * B + b] = o;

        h0 = hn0; h1 = hn1;
        if (t < T_DEC - 1) { xA0 = yv.y; xA1 = yv.z; xA2 = yv.w; xA3 = o; }
    }
}

extern "C" void kernel_launch(void* const* d_in, const int* in_sizes, int n_in,
                              void* d_out, int out_size, void* d_ws, size_t ws_size,
                              hipStream_t stream)
{
    const float* y   = (const float*)d_in[0];
    const float* enc = (const float*)d_in[1];
    const float* hid = (const float*)d_in[2];
    // d_in[3] = batch_ids (int32, unused by reference)
    const float* aW  = (const float*)d_in[4];
    const float* ab  = (const float*)d_in[5];
    const float* cW  = (const float*)d_in[6];
    const float* cb  = (const float*)d_in[7];
    const float* wih = (const float*)d_in[8];
    const float* whh = (const float*)d_in[9];
    const float* bih = (const float*)d_in[10];
    const float* bhh = (const float*)d_in[11];
    const float* fW  = (const float*)d_in[12];
    const float* fb  = (const float*)d_in[13];
    float* out = (float*)d_out;

    // d_ws intentionally unused: P now lives in LDS per-block.
    (void)d_ws; (void)ws_size;

    fused_kernel<<<B / 16, 256, 0, stream>>>(
        y, hid, enc, aW, ab, cW, cb, wih, whh, bih, bhh, fW, fb, out);
}